// Round 3
// baseline (54.017 us; speedup 1.0000x reference)
//
#include <hip/hip_runtime.h>

// Problem constants (from the reference)
constexpr int Bc = 16;
constexpr int Ac = 3;
constexpr int Cc = 80;
constexpr int Hc = 76;
constexpr int Wc = 76;
constexpr int HWc = Hc * Wc;          // 5776
constexpr int Nc  = Ac * HWc;         // 17328
constexpr int CH  = 5 + Cc;           // 85 channels per anchor
constexpr float SCALE_XY = 1.2f;

constexpr int TILE   = 64;            // hw positions staged per block
constexpr int ROWF   = TILE + 4;      // padded LDS row (floats) -> 2-way max bank alias
constexpr int NTILES = (HWc + TILE - 1) / TILE;   // 91 (last tile = 16 locs)

// anchors reshaped (A,2): (w,h) pairs
__constant__ float kAnchorW[Ac] = {1.5f, 2.375f, 5.0f};
__constant__ float kAnchorH[Ac] = {2.0f, 4.5f, 3.5f};

__device__ __forceinline__ float sigmoidf_(float x) {
    return 1.0f / (1.0f + __expf(-x));
}

__global__ __launch_bounds__(256) void yolo_kernel(
    const float* __restrict__ in,   // [B, A*CH, H, W]
    float* __restrict__ boxes,      // [B, N, 1, 4]
    float* __restrict__ confs)      // [B, N, C]
{
    __shared__ float lds[CH * ROWF];            // 23,120 B -> 6 blocks/CU

    const int tid  = threadIdx.x;
    const int tile = blockIdx.x % NTILES;
    const int ba   = blockIdx.x / NTILES;       // b*Ac + a
    const int a    = ba % Ac;
    const int b    = ba / Ac;
    const int hw0  = tile * TILE;

    const float* pin = in + (size_t)ba * CH * HWc;

    // ---- stage: 85 channels x TILE floats, fully-coalesced float4 loads ----
    // CH*(TILE/4) = 1360 float4 elements, 256 threads -> 6 iterations
    #pragma unroll 2
    for (int i = tid; i < CH * (TILE / 4); i += 256) {
        const int ch = i >> 4;                  // 16 float4 per channel row
        const int j  = (i & 15) * 4;
        if (hw0 + j < HWc) {                    // tail tile: only first 16 floats valid
            float4 t = *reinterpret_cast<const float4*>(pin + (size_t)ch * HWc + hw0 + j);
            *reinterpret_cast<float4*>(&lds[ch * ROWF + j]) = t;
        }
    }
    __syncthreads();

    // ---- compute: 4 lanes per location, 20 classes per lane ----
    const int q   = tid & 3;
    const int loc = tid >> 2;                   // 0..63
    const int hw  = hw0 + loc;
    if (hw >= HWc) return;                      // only diverges in the last tile

    const int x = hw % Wc;
    const int y = hw / Wc;

    float v[20];
    float m = -3.402823466e+38f;
    #pragma unroll
    for (int c = 0; c < 20; ++c) {
        v[c] = lds[(5 + q * 20 + c) * ROWF + loc];
        m = fmaxf(m, v[c]);
    }
    m = fmaxf(m, __shfl_xor(m, 1));
    m = fmaxf(m, __shfl_xor(m, 2));

    float s = 0.0f;
    #pragma unroll
    for (int c = 0; c < 20; ++c) {
        v[c] = __expf(v[c] - m);
        s += v[c];
    }
    s += __shfl_xor(s, 1);
    s += __shfl_xor(s, 2);

    const float det   = sigmoidf_(lds[4 * ROWF + loc]);
    const float scale = det / s;

    const int n = a * HWc + hw;                 // detection index within batch

    float* cp = &confs[((size_t)b * Nc + n) * Cc + q * 20];
    #pragma unroll
    for (int c = 0; c < 20; c += 4) {
        float4 t = make_float4(v[c] * scale, v[c + 1] * scale,
                               v[c + 2] * scale, v[c + 3] * scale);
        *reinterpret_cast<float4*>(&cp[c]) = t;
    }

    if (q == 0) {
        const float o0 = lds[0 * ROWF + loc];
        const float o1 = lds[1 * ROWF + loc];
        const float o2 = lds[2 * ROWF + loc];
        const float o3 = lds[3 * ROWF + loc];

        const float bx = (sigmoidf_(o0) * SCALE_XY - 0.5f * (SCALE_XY - 1.0f) + (float)x) * (1.0f / (float)Wc);
        const float by = (sigmoidf_(o1) * SCALE_XY - 0.5f * (SCALE_XY - 1.0f) + (float)y) * (1.0f / (float)Hc);
        const float bw = __expf(o2) * kAnchorW[a] * (1.0f / (float)Wc);
        const float bh = __expf(o3) * kAnchorH[a] * (1.0f / (float)Hc);

        const float bx1 = bx - bw * 0.5f;
        const float by1 = by - bh * 0.5f;
        const float bx2 = bx1 + bw;
        const float by2 = by1 + bh;

        float4 box = make_float4(bx1, by1, bx2, by2);
        *reinterpret_cast<float4*>(&boxes[((size_t)b * Nc + n) * 4]) = box;
    }
}

extern "C" void kernel_launch(void* const* d_in, const int* in_sizes, int n_in,
                              void* d_out, int out_size, void* d_ws, size_t ws_size,
                              hipStream_t stream) {
    const float* in = (const float*)d_in[0];
    float* out = (float*)d_out;

    float* boxes = out;                                  // B*N*1*4 floats
    float* confs = out + (size_t)Bc * Nc * 4;            // B*N*C floats

    const int blocks = Bc * Ac * NTILES;                 // 48 * 91 = 4368
    yolo_kernel<<<blocks, 256, 0, stream>>>(in, boxes, confs);
}

// Round 4
// 36.670 us; speedup vs baseline: 1.4731x; 1.4731x over previous
//
#include <hip/hip_runtime.h>

// Problem constants (from the reference)
constexpr int Bc = 16;
constexpr int Ac = 3;
constexpr int Cc = 80;
constexpr int Hc = 76;
constexpr int Wc = 76;
constexpr int HWc = Hc * Wc;          // 5776
constexpr int Nc  = Ac * HWc;         // 17328
constexpr int CH  = 5 + Cc;           // 85
constexpr float SCALE_XY = 1.2f;

constexpr int LOCS = 64;              // locations per block
constexpr int RSF  = 84;              // LDS row stride in floats (336B, 16B-aligned)
constexpr int TOTAL_LOC = Bc * Ac * HWc;      // 277248
constexpr int NBLK = TOTAL_LOC / LOCS;        // 4332, exact

// anchors reshaped (A,2): (w,h) pairs
__constant__ float kAnchorW[Ac] = {1.5f, 2.375f, 5.0f};
__constant__ float kAnchorH[Ac] = {2.0f, 4.5f, 3.5f};

__device__ __forceinline__ float sigmoidf_(float x) {
    return 1.0f / (1.0f + __expf(-x));
}

__global__ __launch_bounds__(256) void yolo_kernel(
    const float* __restrict__ in,   // [B, A*CH, H, W]
    float* __restrict__ boxes,      // [B, N, 1, 4]  (= flat_loc*4)
    float* __restrict__ confs)      // [B, N, C]     (= flat_loc*80)
{
    __shared__ float lds[LOCS * RSF];   // 21504 B -> 7 blocks/CU

    const int tid  = threadIdx.x;
    const int q    = tid & 3;           // class quarter
    const int loc  = tid >> 2;          // 0..63
    const int flat = blockIdx.x * LOCS + loc;   // linear (b,a,hw)

    const int hw = flat % HWc;
    const int ba = flat / HWc;          // b*Ac + a
    const int a  = ba % Ac;

    // ---- direct, line-efficient reads (R2 pattern) ----
    const float* p = in + (size_t)ba * CH * HWc + hw;

    float v[20];
    float m = -3.402823466e+38f;
    #pragma unroll
    for (int c = 0; c < 20; ++c) {
        v[c] = p[(5 + q * 20 + c) * HWc];
        m = fmaxf(m, v[c]);
    }
    m = fmaxf(m, __shfl_xor(m, 1));
    m = fmaxf(m, __shfl_xor(m, 2));

    float s = 0.0f;
    #pragma unroll
    for (int c = 0; c < 20; ++c) {
        v[c] = __expf(v[c] - m);
        s += v[c];
    }
    s += __shfl_xor(s, 1);
    s += __shfl_xor(s, 2);

    const float det   = sigmoidf_(p[4 * HWc]);   // same addr across the 4-lane group
    const float scale = det / s;

    // ---- stage scaled confs into LDS (b128 writes, near-even bank spread) ----
    float* row = &lds[loc * RSF + q * 20];
    #pragma unroll
    for (int k = 0; k < 5; ++k) {
        float4 t = make_float4(v[4*k] * scale, v[4*k + 1] * scale,
                               v[4*k + 2] * scale, v[4*k + 3] * scale);
        *reinterpret_cast<float4*>(&row[k * 4]) = t;
    }

    // ---- boxes: one lane per location, direct (256B-contiguous per wave) ----
    if (q == 0) {
        const int x = hw % Wc;
        const int y = hw / Wc;
        const float o0 = p[0 * HWc];
        const float o1 = p[1 * HWc];
        const float o2 = p[2 * HWc];
        const float o3 = p[3 * HWc];

        const float bx = (sigmoidf_(o0) * SCALE_XY - 0.5f * (SCALE_XY - 1.0f) + (float)x) * (1.0f / (float)Wc);
        const float by = (sigmoidf_(o1) * SCALE_XY - 0.5f * (SCALE_XY - 1.0f) + (float)y) * (1.0f / (float)Hc);
        const float bw = __expf(o2) * kAnchorW[a] * (1.0f / (float)Wc);
        const float bh = __expf(o3) * kAnchorH[a] * (1.0f / (float)Hc);

        const float bx1 = bx - bw * 0.5f;
        const float by1 = by - bh * 0.5f;
        const float bx2 = bx1 + bw;
        const float by2 = by1 + bh;

        float4 box = make_float4(bx1, by1, bx2, by2);
        *reinterpret_cast<float4*>(&boxes[(size_t)flat * 4]) = box;
    }

    __syncthreads();

    // ---- write-out: 64 locs x 80 floats = 1280 float4, fully coalesced:
    // each store instruction covers 1KB contiguous global memory ----
    float* cdst = confs + (size_t)blockIdx.x * LOCS * Cc;
    #pragma unroll
    for (int k = 0; k < 5; ++k) {
        const int g  = tid + k * 256;          // float4 index 0..1279
        const int lp = g / 20;                 // source row (location)
        const int u  = g - lp * 20;            // float4 slot within row
        float4 t = *reinterpret_cast<const float4*>(&lds[lp * RSF + u * 4]);
        *reinterpret_cast<float4*>(&cdst[(size_t)g * 4]) = t;
    }
}

extern "C" void kernel_launch(void* const* d_in, const int* in_sizes, int n_in,
                              void* d_out, int out_size, void* d_ws, size_t ws_size,
                              hipStream_t stream) {
    const float* in = (const float*)d_in[0];
    float* out = (float*)d_out;

    float* boxes = out;                                  // B*N*1*4 floats
    float* confs = out + (size_t)Bc * Nc * 4;            // B*N*C floats

    yolo_kernel<<<NBLK, 256, 0, stream>>>(in, boxes, confs);
}

// Round 6
// 35.974 us; speedup vs baseline: 1.5015x; 1.0193x over previous
//
#include <hip/hip_runtime.h>

// Problem constants (from the reference)
constexpr int Bc = 16;
constexpr int Ac = 3;
constexpr int Cc = 80;
constexpr int Hc = 76;
constexpr int Wc = 76;
constexpr int HWc = Hc * Wc;          // 5776
constexpr int Nc  = Ac * HWc;         // 17328
constexpr int CH  = 5 + Cc;           // 85
constexpr float SCALE_XY = 1.2f;

constexpr int LOCS = 64;              // locations per block
constexpr int RSF  = 84;              // LDS row stride in floats (336B, 16B-aligned)
constexpr int TOTAL_LOC = Bc * Ac * HWc;      // 277248
constexpr int NBLK = TOTAL_LOC / LOCS;        // 4332, exact

typedef float f32x4 __attribute__((ext_vector_type(4)));   // nt-store-compatible

// anchors reshaped (A,2): (w,h) pairs
__constant__ float kAnchorW[Ac] = {1.5f, 2.375f, 5.0f};
__constant__ float kAnchorH[Ac] = {2.0f, 4.5f, 3.5f};

__device__ __forceinline__ float sigmoidf_(float x) {
    return 1.0f / (1.0f + __expf(-x));
}

__global__ __launch_bounds__(256) void yolo_kernel(
    const float* __restrict__ in,   // [B, A*CH, H, W]
    float* __restrict__ boxes,      // [B, N, 1, 4]  (= flat_loc*4)
    float* __restrict__ confs)      // [B, N, C]     (= flat_loc*80)
{
    __shared__ float lds[LOCS * RSF];   // 21504 B -> 7 blocks/CU

    const int tid  = threadIdx.x;
    const int q    = tid & 3;           // class quarter
    const int loc  = tid >> 2;          // 0..63
    const int flat = blockIdx.x * LOCS + loc;   // linear (b,a,hw)

    const int hw = flat % HWc;
    const int ba = flat / HWc;          // b*Ac + a
    const int a  = ba % Ac;

    // ---- direct, line-efficient reads ----
    const float* p = in + (size_t)ba * CH * HWc + hw;

    float v[20];
    float m = -3.402823466e+38f;
    #pragma unroll
    for (int c = 0; c < 20; ++c) {
        v[c] = p[(5 + q * 20 + c) * HWc];
        m = fmaxf(m, v[c]);
    }
    m = fmaxf(m, __shfl_xor(m, 1));
    m = fmaxf(m, __shfl_xor(m, 2));

    float s = 0.0f;
    #pragma unroll
    for (int c = 0; c < 20; ++c) {
        v[c] = __expf(v[c] - m);
        s += v[c];
    }
    s += __shfl_xor(s, 1);
    s += __shfl_xor(s, 2);

    const float det   = sigmoidf_(p[4 * HWc]);   // same addr across the 4-lane group
    const float scale = det / s;

    // ---- stage scaled confs into LDS (b128 writes, near-even bank spread) ----
    float* row = &lds[loc * RSF + q * 20];
    #pragma unroll
    for (int k = 0; k < 5; ++k) {
        f32x4 t = {v[4*k] * scale, v[4*k + 1] * scale,
                   v[4*k + 2] * scale, v[4*k + 3] * scale};
        *reinterpret_cast<f32x4*>(&row[k * 4]) = t;
    }

    // ---- boxes: one lane per location, nontemporal (output never re-read) ----
    if (q == 0) {
        const int x = hw % Wc;
        const int y = hw / Wc;
        const float o0 = p[0 * HWc];
        const float o1 = p[1 * HWc];
        const float o2 = p[2 * HWc];
        const float o3 = p[3 * HWc];

        const float bx = (sigmoidf_(o0) * SCALE_XY - 0.5f * (SCALE_XY - 1.0f) + (float)x) * (1.0f / (float)Wc);
        const float by = (sigmoidf_(o1) * SCALE_XY - 0.5f * (SCALE_XY - 1.0f) + (float)y) * (1.0f / (float)Hc);
        const float bw = __expf(o2) * kAnchorW[a] * (1.0f / (float)Wc);
        const float bh = __expf(o3) * kAnchorH[a] * (1.0f / (float)Hc);

        const float bx1 = bx - bw * 0.5f;
        const float by1 = by - bh * 0.5f;
        const float bx2 = bx1 + bw;
        const float by2 = by1 + bh;

        f32x4 box = {bx1, by1, bx2, by2};
        __builtin_nontemporal_store(box, reinterpret_cast<f32x4*>(&boxes[(size_t)flat * 4]));
    }

    __syncthreads();

    // ---- write-out: 64 locs x 80 floats = 1280 float4, fully coalesced,
    // nontemporal so the 95MB output stream doesn't evict the L3-resident input ----
    float* cdst = confs + (size_t)blockIdx.x * LOCS * Cc;
    #pragma unroll
    for (int k = 0; k < 5; ++k) {
        const int g  = tid + k * 256;          // float4 index 0..1279
        const int lp = g / 20;                 // source row (location)
        const int u  = g - lp * 20;            // float4 slot within row
        f32x4 t = *reinterpret_cast<const f32x4*>(&lds[lp * RSF + u * 4]);
        __builtin_nontemporal_store(t, reinterpret_cast<f32x4*>(&cdst[(size_t)g * 4]));
    }
}

extern "C" void kernel_launch(void* const* d_in, const int* in_sizes, int n_in,
                              void* d_out, int out_size, void* d_ws, size_t ws_size,
                              hipStream_t stream) {
    const float* in = (const float*)d_in[0];
    float* out = (float*)d_out;

    float* boxes = out;                                  // B*N*1*4 floats
    float* confs = out + (size_t)Bc * Nc * 4;            // B*N*C floats

    yolo_kernel<<<NBLK, 256, 0, stream>>>(in, boxes, confs);
}